// Round 7
// baseline (11.623 us; speedup 1.0000x reference)
//
#include <hip/hip_runtime.h>
#include <math.h>

#define NROWS 8192
#define KP1   17
#define RPB_A 32    // rows per block in kernel A (512 threads / 16 lanes)

// ---- Kernel A: 16 lanes per row; also produces per-block partial exp-sums.
// 256 blocks x 512 threads. Lane k gathers idx[k]; idx[16] is wave-uniform
// per 16-lane group (broadcast line) and added at lane 0.
__global__ __launch_bounds__(512) void gather_sum_kernel(
    const float* __restrict__ data,
    const int* __restrict__ nidx,
    float* __restrict__ a_raw,
    float* __restrict__ partial)
{
    __shared__ float lds_exp[RPB_A];

    const int t   = threadIdx.x;
    int tid = blockIdx.x * 512 + t;
    int row = tid >> 4;
    int k   = tid & 15;

    const int* ip = nidx + row * KP1;
    int c0  = ip[k];        // per-lane index
    int c16 = ip[16];       // uniform per 16-lane group: broadcast line

    const float* rp = data + (size_t)row * NROWS;
    float v   = rp[c0];
    float v16 = rp[c16];

    v += (k == 0) ? v16 : 0.0f;

    #pragma unroll
    for (int off = 8; off > 0; off >>= 1)
        v += __shfl_down(v, off, 16);

    if (k == 0) {
        a_raw[row] = v;
        lds_exp[t >> 4] = expf(v);   // no max-subtraction: |A_raw| <= ~25
    }
    __syncthreads();

    // block partial: fixed shuffle tree over 32 row-exps (deterministic)
    if (t < 32) {
        float p = lds_exp[t];
        #pragma unroll
        for (int off = 16; off > 0; off >>= 1)
            p += __shfl_down(p, off, 32);
        if (t == 0) partial[blockIdx.x] = p;
    }
}

// ---- Kernel B: 8 blocks x 1024 threads. Wave 0 reduces all 256 partials via
// float4 loads (single wave, no LDS tree); one LDS broadcast + syncthreads;
// each thread writes one alpha element. Fixed reduction order (deterministic).
__global__ __launch_bounds__(1024) void softmax_norm_kernel(
    const float* __restrict__ a_raw,
    const float* __restrict__ partial,
    float* __restrict__ alpha)
{
    __shared__ float s_inv;
    const int t   = threadIdx.x;
    const int row = blockIdx.x * 1024 + t;

    float e = expf(a_raw[row]);      // independent chain, issues immediately

    if (t < 64) {
        const float4* p4 = (const float4*)partial;   // 256 floats = 64 float4
        float4 x = p4[t];
        float s = (x.x + x.y) + (x.z + x.w);
        #pragma unroll
        for (int off = 32; off > 0; off >>= 1)
            s += __shfl_down(s, off, 64);
        if (t == 0) s_inv = 1.0f / s;
    }
    __syncthreads();

    alpha[row] = e * s_inv;
}

extern "C" void kernel_launch(void* const* d_in, const int* in_sizes, int n_in,
                              void* d_out, int out_size, void* d_ws, size_t ws_size,
                              hipStream_t stream) {
    const float* data = (const float*)d_in[0];
    const int*   nidx = (const int*)d_in[1];
    float* alpha   = (float*)d_out;            // output 0: alpha (8192)
    float* a_raw   = (float*)d_out + NROWS;    // output 1: A_raw (8192)
    float* partial = (float*)d_ws;             // 256 floats

    gather_sum_kernel<<<(NROWS * 16) / 512, 512, 0, stream>>>(data, nidx, a_raw, partial);
    softmax_norm_kernel<<<8, 1024, 0, stream>>>(a_raw, partial, alpha);
}